// Round 8
// baseline (522.256 us; speedup 1.0000x reference)
//
#include <hip/hip_runtime.h>

#define HID 128
#define LN_EPS 1e-5f

typedef __attribute__((ext_vector_type(8))) short bf16x8;
typedef __attribute__((ext_vector_type(4))) float f32x4;

__device__ __forceinline__ ushort f2bf(float v) {
  union { float f; uint u; } x; x.f = v;
  uint r = x.u + 0x7fffu + ((x.u >> 16) & 1u);   // RNE
  return (ushort)(r >> 16);
}
__device__ __forceinline__ float bf2f(ushort u) {
  union { uint u; float f; } x; x.u = (uint)u << 16; return x.f;
}

// ---------------- graph preprocessing ----------------

__global__ void k_init(int* __restrict__ cnt, int n) {
  int i = blockIdx.x * 256 + threadIdx.x;
  if (i < n) cnt[i] = 0;
}

// counts AND records each edge's rank within its dst list (atomic return value)
__global__ void k_count(const int* __restrict__ dst, int* __restrict__ cnt,
                        int* __restrict__ rank, int E) {
  int e = blockIdx.x * 256 + threadIdx.x;
  if (e < E) rank[e] = atomicAdd(&cnt[dst[e]], 1);
}

__global__ void k_dinv(const int* __restrict__ cnt, float* __restrict__ dinv, int n) {
  int i = blockIdx.x * 256 + threadIdx.x;
  if (i < n) dinv[i] = rsqrtf((float)cnt[i] + 1.0f);   // +1 = self loop
}

// hierarchical exclusive scan of cnt -> row_start (512 elems per block)
__global__ void k_bsum(const int* __restrict__ cnt, int* __restrict__ bsum, int n) {
  __shared__ int red[256];
  int b = blockIdx.x, t = threadIdx.x;
  int i = b * 512 + t * 2;
  int s = ((i < n) ? cnt[i] : 0) + ((i + 1 < n) ? cnt[i + 1] : 0);
  red[t] = s;
  __syncthreads();
  for (int off = 128; off > 0; off >>= 1) {
    if (t < off) red[t] += red[t + off];
    __syncthreads();
  }
  if (t == 0) bsum[b] = red[0];
}

__global__ void k_bscan(int* __restrict__ bsum, int nb) {
  __shared__ int buf[1024];
  int t = threadIdx.x;
  int v = (t < nb) ? bsum[t] : 0;
  buf[t] = v;
  __syncthreads();
  for (int off = 1; off < 1024; off <<= 1) {
    int u = (t >= off) ? buf[t - off] : 0;
    __syncthreads();
    buf[t] += u;
    __syncthreads();
  }
  if (t < nb) bsum[t] = buf[t] - v;   // exclusive
}

__global__ void k_rowstart(const int* __restrict__ cnt, const int* __restrict__ bsum,
                           int* __restrict__ row_start, int n) {
  __shared__ int buf[256];
  int b = blockIdx.x, t = threadIdx.x;
  int i = b * 512 + t * 2;
  int c0 = (i < n) ? cnt[i] : 0;
  int c1 = (i + 1 < n) ? cnt[i + 1] : 0;
  int s = c0 + c1;
  buf[t] = s;
  __syncthreads();
  int mine = s;
  for (int off = 1; off < 256; off <<= 1) {
    int u = (t >= off) ? buf[t - off] : 0;
    __syncthreads();
    buf[t] += u;
    __syncthreads();
  }
  int ex = buf[t] - mine + bsum[b];
  if (i < n) row_start[i] = ex;
  if (i + 1 < n) row_start[i + 1] = ex + c0;
}

// atomic-free scatter: one 8B record per edge at row_start[dst] + rank[e]
__global__ void k_scatter(const int* __restrict__ src, const int* __restrict__ dst,
                          const int* __restrict__ row_start, const int* __restrict__ rank,
                          const float* __restrict__ dinv,
                          uint2* __restrict__ rec, int E) {
  int e = blockIdx.x * 256 + threadIdx.x;
  if (e < E) {
    int d = dst[e], s = src[e];
    int pos = row_start[d] + rank[e];
    union { float f; uint u; } w; w.f = dinv[s] * dinv[d];
    rec[pos] = make_uint2((uint)s, w.u);
  }
}

// ---------------- weight prep: bf16, MFMA-fragment-ordered ----------------
// Fragment layout: frag[(n*KS + ks)*512 + lane*8 + j] = W^T-element for
//   k = ks*32 + (lane>>4)*8 + j,  col = n*16 + (lane&15)
__global__ void k_prep_w(const float* __restrict__ lin_in_w,
                         const float* __restrict__ conv_w, const float* __restrict__ lin_w,
                         const float* __restrict__ conv_b, const float* __restrict__ lin_b,
                         ushort* __restrict__ wt_in, ushort* __restrict__ wt_l,
                         float* __restrict__ bsum, int L) {
  int tid = blockIdx.x * 256 + threadIdx.x;
  int total = L * 128 * 256;
  if (tid < total) {
    int l = tid >> 15;              // /32768
    int idx = tid & 32767;
    int n = idx >> 12;              // 8 col-blocks
    int r = idx & 4095;
    int ks = r >> 9;                // 8 k-steps (K=256)
    int r2 = r & 511;
    int lane = r2 >> 3;
    int j = r2 & 7;
    int k2 = ks * 32 + (lane >> 4) * 8 + j;
    int c = n * 16 + (lane & 15);
    float v = (k2 < 128) ? conv_w[((size_t)l * 128 + k2) * 128 + c]
                         : lin_w[((size_t)l * 128 + (k2 - 128)) * 128 + c];
    wt_l[tid] = f2bf(v);
  }
  if (tid < 128 * 128) {
    int n = tid >> 11;              // 8 col-blocks
    int r = tid & 2047;
    int ks = r >> 9;                // 4 k-steps (K=128)
    int r2 = r & 511;
    int lane = r2 >> 3;
    int j = r2 & 7;
    int k = ks * 32 + (lane >> 4) * 8 + j;
    int c = n * 16 + (lane & 15);
    wt_in[tid] = f2bf(lin_in_w[k * 128 + c]);
  }
  if (tid < L * 128) bsum[tid] = conv_b[tid] + lin_b[tid];
}

// ---------------- aggregation: s = D^-1/2 (A+I) D^-1/2 x  (bf16 in/out) ----------------
// XCD-chunked: block handles col-chunk c = blockIdx.x & 3 (32 cols = one 64B line/row).
// With round-robin block->XCD dispatch, chunk c lands on XCDs {c, c+4}; hot X-slice
// = N*64B = 3.2MB < 4MB XCD-L2 -> gathers become L2 hits. rec/Sout use nontemporal
// to protect the resident slice. Wave: 8 edges x 8 lanes (uint2 = 4 cols each).
__global__ void k_agg(const ushort* __restrict__ X, const int* __restrict__ row_start,
                      const int* __restrict__ cnt, const float* __restrict__ dinv,
                      const uint2* __restrict__ rec, ushort* __restrict__ Sout, int n) {
  const int chunk = blockIdx.x & 3;
  const int node = (blockIdx.x >> 2) * 4 + (threadIdx.x >> 6);
  if (node >= n) return;
  const int lane = threadIdx.x & 63;
  const int esub = lane >> 3;        // 0..7: which edge of the 8-group
  const int cg   = lane & 7;         // col group: 4 bf16 cols each
  const int colb = chunk * 32 + cg * 4;

  float a0 = 0.f, a1 = 0.f, a2 = 0.f, a3 = 0.f;
  const int start = row_start[node];
  const int m = cnt[node];
  const int last = start + m - 1;
  const ulong* recq = reinterpret_cast<const ulong*>(rec);

  for (int e = 0; e < m; e += 16) {
    int ia = start + e + esub;
    int ib = ia + 8;
    ulong qa = __builtin_nontemporal_load(recq + min(ia, last));
    ulong qb = __builtin_nontemporal_load(recq + min(ib, last));
    uint sa = (uint)qa, sb = (uint)qb;
    union { uint u; float f; } wa, wb;
    wa.u = (e + esub < m) ? (uint)(qa >> 32) : 0u;
    wb.u = (e + 8 + esub < m) ? (uint)(qb >> 32) : 0u;
    uint2 ua = *reinterpret_cast<const uint2*>(X + (size_t)sa * HID + colb);
    uint2 ub = *reinterpret_cast<const uint2*>(X + (size_t)sb * HID + colb);
    a0 = fmaf(wa.f, bf2f((ushort)(ua.x & 0xffff)), a0);
    a1 = fmaf(wa.f, bf2f((ushort)(ua.x >> 16)), a1);
    a2 = fmaf(wa.f, bf2f((ushort)(ua.y & 0xffff)), a2);
    a3 = fmaf(wa.f, bf2f((ushort)(ua.y >> 16)), a3);
    a0 = fmaf(wb.f, bf2f((ushort)(ub.x & 0xffff)), a0);
    a1 = fmaf(wb.f, bf2f((ushort)(ub.x >> 16)), a1);
    a2 = fmaf(wb.f, bf2f((ushort)(ub.y & 0xffff)), a2);
    a3 = fmaf(wb.f, bf2f((ushort)(ub.y >> 16)), a3);
  }
  // reduce across the 8 edge-subgroups (lane bits 3..5)
#pragma unroll
  for (int s = 8; s < 64; s <<= 1) {
    a0 += __shfl_xor(a0, s);
    a1 += __shfl_xor(a1, s);
    a2 += __shfl_xor(a2, s);
    a3 += __shfl_xor(a3, s);
  }
  if (esub == 0) {
    float dv = dinv[node];
    float d2 = dv * dv;
    uint2 u = *reinterpret_cast<const uint2*>(X + (size_t)node * HID + colb);
    a0 = fmaf(d2, bf2f((ushort)(u.x & 0xffff)), a0);
    a1 = fmaf(d2, bf2f((ushort)(u.x >> 16)), a1);
    a2 = fmaf(d2, bf2f((ushort)(u.y & 0xffff)), a2);
    a3 = fmaf(d2, bf2f((ushort)(u.y >> 16)), a3);
    ulong o = (ulong)((uint)f2bf(a0) | ((uint)f2bf(a1) << 16)) |
              ((ulong)((uint)f2bf(a2) | ((uint)f2bf(a3) << 16)) << 32);
    __builtin_nontemporal_store(o,
        reinterpret_cast<ulong*>(Sout + (size_t)node * HID + colb));
  }
}

// ---------------- MFMA GEMM kernels ----------------
// per block: 4 waves, 16 rows each; per wave: full 128 output cols.
// A-frag: lane holds A[r0 + (l&15)][ks*32 + (l>>4)*8 .. +7]
// B-frag: coalesced from fragment-ordered WtF
// C: row=(l>>4)*4+q, col=n*16+(l&15) -> LDS transpose for coalesced epilogue

__global__ void __launch_bounds__(256, 2)
k_gemm_in(const float* __restrict__ Xin, const ushort* __restrict__ WtF,
          const float* __restrict__ bias, ushort* __restrict__ Xout, int nrows) {
  __shared__ float lds[4 * 16 * 132];
  const int tid = threadIdx.x;
  const int wid = tid >> 6, lane = tid & 63;
  const int lr = lane & 15, lg = lane >> 4;
  const int r0 = blockIdx.x * 64 + wid * 16;
  const int arow = r0 + lr;
  const bool rowok = arow < nrows;

  bf16x8 a[4];
  {
    const float* xp = Xin + (size_t)arow * HID + lg * 8;
#pragma unroll
    for (int ks = 0; ks < 4; ks++) {
      bf16x8 t;
#pragma unroll
      for (int i = 0; i < 8; i++) t[i] = 0;
      if (rowok) {
        float4 u0 = *reinterpret_cast<const float4*>(xp + ks * 32);
        float4 u1 = *reinterpret_cast<const float4*>(xp + ks * 32 + 4);
        t[0] = (short)f2bf(u0.x); t[1] = (short)f2bf(u0.y);
        t[2] = (short)f2bf(u0.z); t[3] = (short)f2bf(u0.w);
        t[4] = (short)f2bf(u1.x); t[5] = (short)f2bf(u1.y);
        t[6] = (short)f2bf(u1.z); t[7] = (short)f2bf(u1.w);
      }
      a[ks] = t;
    }
  }

  f32x4 acc[8];
#pragma unroll
  for (int n = 0; n < 8; n++) acc[n] = f32x4{0.f, 0.f, 0.f, 0.f};

  const ushort* wb = WtF + lane * 8;
#pragma unroll
  for (int n = 0; n < 8; n++)
#pragma unroll
    for (int ks = 0; ks < 4; ks++) {
      bf16x8 b = *reinterpret_cast<const bf16x8*>(wb + (n * 4 + ks) * 512);
      acc[n] = __builtin_amdgcn_mfma_f32_16x16x32_bf16(a[ks], b, acc[n], 0, 0, 0);
    }

  float* T = lds + wid * (16 * 132);
#pragma unroll
  for (int n = 0; n < 8; n++)
#pragma unroll
    for (int q = 0; q < 4; q++)
      T[(lg * 4 + q) * 132 + n * 16 + lr] = acc[n][q];

  const int c0 = lg * 32;
  const float* Trow = T + lr * 132 + c0;
  const int orow = r0 + lr;
  if (orow < nrows) {
    ushort* xo = Xout + (size_t)orow * HID + c0;
    uint pk[16];
#pragma unroll
    for (int j = 0; j < 8; j++) {
      float4 t = *reinterpret_cast<const float4*>(Trow + j * 4);
      float4 b4 = *reinterpret_cast<const float4*>(bias + c0 + j * 4);
      float o0 = t.x + b4.x, o1 = t.y + b4.y, o2 = t.z + b4.z, o3 = t.w + b4.w;
      pk[j * 2 + 0] = (uint)f2bf(o0) | ((uint)f2bf(o1) << 16);
      pk[j * 2 + 1] = (uint)f2bf(o2) | ((uint)f2bf(o3) << 16);
    }
#pragma unroll
    for (int j = 0; j < 4; j++)
      *reinterpret_cast<uint4*>(xo + j * 8) =
          make_uint4(pk[j * 4 + 0], pk[j * 4 + 1], pk[j * 4 + 2], pk[j * 4 + 3]);
  }
}

__global__ void __launch_bounds__(256, 2)
k_layer(const ushort* __restrict__ S, const ushort* __restrict__ Xin,
        ushort* __restrict__ Xout,
        const ushort* __restrict__ WtF, const float* __restrict__ bsum,
        const float* __restrict__ gamma, const float* __restrict__ beta, int nrows) {
  __shared__ float lds[4 * 16 * 132];
  const int tid = threadIdx.x;
  const int wid = tid >> 6, lane = tid & 63;
  const int lr = lane & 15, lg = lane >> 4;
  const int r0 = blockIdx.x * 64 + wid * 16;
  const int arow = r0 + lr;
  const bool rowok = arow < nrows;

  bf16x8 a[8];
  {
    const ushort* sp = S + (size_t)arow * HID + lg * 8;
    const ushort* xp = Xin + (size_t)arow * HID + lg * 8;
    bf16x8 z;
#pragma unroll
    for (int i = 0; i < 8; i++) z[i] = 0;
#pragma unroll
    for (int ks = 0; ks < 4; ks++)
      a[ks] = rowok ? *reinterpret_cast<const bf16x8*>(sp + ks * 32) : z;
#pragma unroll
    for (int ks = 0; ks < 4; ks++)
      a[4 + ks] = rowok ? *reinterpret_cast<const bf16x8*>(xp + ks * 32) : z;
  }

  f32x4 acc[8];
#pragma unroll
  for (int n = 0; n < 8; n++) acc[n] = f32x4{0.f, 0.f, 0.f, 0.f};

  const ushort* wb = WtF + lane * 8;
#pragma unroll
  for (int n = 0; n < 8; n++)
#pragma unroll
    for (int ks = 0; ks < 8; ks++) {
      bf16x8 b = *reinterpret_cast<const bf16x8*>(wb + (n * 8 + ks) * 512);
      acc[n] = __builtin_amdgcn_mfma_f32_16x16x32_bf16(a[ks], b, acc[n], 0, 0, 0);
    }

  float* T = lds + wid * (16 * 132);
#pragma unroll
  for (int n = 0; n < 8; n++)
#pragma unroll
    for (int q = 0; q < 4; q++)
      T[(lg * 4 + q) * 132 + n * 16 + lr] = acc[n][q];

  // epilogue: lane handles row lr, cols [c0, c0+32)
  const int c0 = lg * 32;
  const float* Trow = T + lr * 132 + c0;
  float v[32];
  float sum = 0.f, sq = 0.f;
#pragma unroll
  for (int j = 0; j < 8; j++) {
    float4 t = *reinterpret_cast<const float4*>(Trow + j * 4);
    float4 b4 = *reinterpret_cast<const float4*>(bsum + c0 + j * 4);
    float x0 = t.x + b4.x, x1 = t.y + b4.y, x2 = t.z + b4.z, x3 = t.w + b4.w;
    v[j * 4 + 0] = x0; v[j * 4 + 1] = x1; v[j * 4 + 2] = x2; v[j * 4 + 3] = x3;
    sum += (x0 + x1) + (x2 + x3);
    sq = fmaf(x0, x0, sq); sq = fmaf(x1, x1, sq);
    sq = fmaf(x2, x2, sq); sq = fmaf(x3, x3, sq);
  }
  sum += __shfl_xor(sum, 16); sq += __shfl_xor(sq, 16);
  sum += __shfl_xor(sum, 32); sq += __shfl_xor(sq, 32);
  const float mean = sum * (1.f / 128.f);
  const float rstd = rsqrtf(sq * (1.f / 128.f) - mean * mean + LN_EPS);

  const int orow = r0 + lr;
  if (orow < nrows) {
    ushort* xo = Xout + (size_t)orow * HID + c0;
    uint pk[16];
#pragma unroll
    for (int j = 0; j < 8; j++) {
      float4 g4 = *reinterpret_cast<const float4*>(gamma + c0 + j * 4);
      float4 b4 = *reinterpret_cast<const float4*>(beta + c0 + j * 4);
      float o0 = fmaxf(fmaf((v[j * 4 + 0] - mean) * rstd, g4.x, b4.x), 0.f);
      float o1 = fmaxf(fmaf((v[j * 4 + 1] - mean) * rstd, g4.y, b4.y), 0.f);
      float o2 = fmaxf(fmaf((v[j * 4 + 2] - mean) * rstd, g4.z, b4.z), 0.f);
      float o3 = fmaxf(fmaf((v[j * 4 + 3] - mean) * rstd, g4.w, b4.w), 0.f);
      pk[j * 2 + 0] = (uint)f2bf(o0) | ((uint)f2bf(o1) << 16);
      pk[j * 2 + 1] = (uint)f2bf(o2) | ((uint)f2bf(o3) << 16);
    }
#pragma unroll
    for (int j = 0; j < 4; j++)
      *reinterpret_cast<uint4*>(xo + j * 8) =
          make_uint4(pk[j * 4 + 0], pk[j * 4 + 1], pk[j * 4 + 2], pk[j * 4 + 3]);
  }
}

// ---------------- JK sum: out = x1 + x2 + x3 (bf16 -> f32) ----------------
__global__ void k_jk(const ushort* __restrict__ a, const ushort* __restrict__ b,
                     const ushort* __restrict__ c, float* __restrict__ out, int total8) {
  int i = blockIdx.x * 256 + threadIdx.x;
  if (i >= total8) return;
  uint4 ua = *reinterpret_cast<const uint4*>(a + (size_t)i * 8);
  uint4 ub = *reinterpret_cast<const uint4*>(b + (size_t)i * 8);
  uint4 uc = *reinterpret_cast<const uint4*>(c + (size_t)i * 8);
  float o[8];
  const uint pa[4] = {ua.x, ua.y, ua.z, ua.w};
  const uint pb[4] = {ub.x, ub.y, ub.z, ub.w};
  const uint pc[4] = {uc.x, uc.y, uc.z, uc.w};
#pragma unroll
  for (int j = 0; j < 4; j++) {
    o[j * 2 + 0] = bf2f((ushort)(pa[j] & 0xffff)) + bf2f((ushort)(pb[j] & 0xffff)) +
                   bf2f((ushort)(pc[j] & 0xffff));
    o[j * 2 + 1] = bf2f((ushort)(pa[j] >> 16)) + bf2f((ushort)(pb[j] >> 16)) +
                   bf2f((ushort)(pc[j] >> 16));
  }
  float* op = out + (size_t)i * 8;
  *reinterpret_cast<float4*>(op) = make_float4(o[0], o[1], o[2], o[3]);
  *reinterpret_cast<float4*>(op + 4) = make_float4(o[4], o[5], o[6], o[7]);
}

// ---------------- launcher ----------------

extern "C" void kernel_launch(void* const* d_in, const int* in_sizes, int n_in,
                              void* d_out, int out_size, void* d_ws, size_t ws_size,
                              hipStream_t stream) {
  const float* x_in     = (const float*)d_in[0];
  const int*   edge     = (const int*)d_in[1];
  const float* lin_in_w = (const float*)d_in[2];
  const float* lin_in_b = (const float*)d_in[3];
  const float* conv_w   = (const float*)d_in[4];
  const float* conv_b   = (const float*)d_in[5];
  const float* lin_w    = (const float*)d_in[6];
  const float* lin_b    = (const float*)d_in[7];
  const float* ln_g     = (const float*)d_in[8];
  const float* ln_b     = (const float*)d_in[9];

  int N = in_sizes[0] / HID;
  int E = in_sizes[1] / 2;
  int L = in_sizes[4] / (HID * HID);

  const int* src = edge;
  const int* dst = edge + E;

  char* ws = (char*)d_ws;
  size_t off = 0;
  auto alloc = [&](size_t bytes) -> void* {
    void* p = (void*)(ws + off);
    off += (bytes + 255) & ~(size_t)255;
    return p;
  };
  int*    cnt       = (int*)alloc((size_t)N * 4);
  int*    rank      = (int*)alloc((size_t)E * 4);
  int*    row_start = (int*)alloc((size_t)N * 4);
  float*  dinv      = (float*)alloc((size_t)N * 4);
  int*    blocksum  = (int*)alloc(4096);
  uint2*  rec       = (uint2*)alloc((size_t)E * 8);
  ushort* xb0       = (ushort*)alloc((size_t)N * HID * 2);
  ushort* xb1       = (ushort*)alloc((size_t)N * HID * 2);
  ushort* xb2       = (ushort*)alloc((size_t)N * HID * 2);
  ushort* sbuf      = (ushort*)alloc((size_t)N * HID * 2);
  ushort* wt_in     = (ushort*)alloc((size_t)128 * 128 * 2);
  ushort* wt_l      = (ushort*)alloc((size_t)L * 128 * 256 * 2);
  float*  bsum      = (float*)alloc((size_t)L * 128 * 4);
  (void)ws_size; (void)n_in; (void)out_size;

  int nb_n = (N + 255) / 256;
  int nb_e = (E + 255) / 256;
  int nbs  = (N + 511) / 512;
  int nb_g = (N + 63) / 64;
  int nb_w = (L * 128 * 256 + 255) / 256;
  int nb_a = 4 * ((N + 3) / 4);   // 4 col-chunks x node-groups
  int total8 = N * HID / 8;
  int nb_j = (total8 + 255) / 256;

  k_init<<<nb_n, 256, 0, stream>>>(cnt, N);
  k_count<<<nb_e, 256, 0, stream>>>(dst, cnt, rank, E);
  k_dinv<<<nb_n, 256, 0, stream>>>(cnt, dinv, N);
  k_bsum<<<nbs, 256, 0, stream>>>(cnt, blocksum, N);
  k_bscan<<<1, 1024, 0, stream>>>(blocksum, nbs);
  k_rowstart<<<nbs, 256, 0, stream>>>(cnt, blocksum, row_start, N);
  k_scatter<<<nb_e, 256, 0, stream>>>(src, dst, row_start, rank, dinv, rec, E);
  k_prep_w<<<nb_w, 256, 0, stream>>>(lin_in_w, conv_w, lin_w, conv_b, lin_b,
                                     wt_in, wt_l, bsum, L);

  k_gemm_in<<<nb_g, 256, 0, stream>>>(x_in, wt_in, lin_in_b, xb0, N);

  // rotate: layer i reads xprev, writes xcur; JK needs the 3 layer outputs
  ushort* xin_b[3]  = {xb0, xb1, xb2};
  ushort* xout_b[3] = {xb1, xb2, xb0};
  for (int i = 0; i < L; i++) {
    k_agg<<<nb_a, 256, 0, stream>>>(xin_b[i], row_start, cnt, dinv, rec, sbuf, N);
    k_layer<<<nb_g, 256, 0, stream>>>(sbuf, xin_b[i], xout_b[i],
        wt_l + (size_t)i * 128 * 256, bsum + (size_t)i * 128,
        ln_g + (size_t)i * HID, ln_b + (size_t)i * HID, N);
  }
  k_jk<<<nb_j, 256, 0, stream>>>(xb1, xb2, xb0, (float*)d_out, total8);
}

// Round 9
// 361.163 us; speedup vs baseline: 1.4460x; 1.4460x over previous
//
#include <hip/hip_runtime.h>

#define HID 128
#define LN_EPS 1e-5f

typedef __attribute__((ext_vector_type(8))) short bf16x8;
typedef __attribute__((ext_vector_type(4))) float f32x4;

__device__ __forceinline__ ushort f2bf(float v) {
  union { float f; uint u; } x; x.f = v;
  uint r = x.u + 0x7fffu + ((x.u >> 16) & 1u);   // RNE
  return (ushort)(r >> 16);
}
__device__ __forceinline__ float bf2f(ushort u) {
  union { uint u; float f; } x; x.u = (uint)u << 16; return x.f;
}

// ---------------- graph preprocessing ----------------

__global__ void k_init(int* __restrict__ cnt, int n) {
  int i = blockIdx.x * 256 + threadIdx.x;
  if (i < n) cnt[i] = 0;
}

// counts AND records each edge's rank within its dst list (atomic return value)
__global__ void k_count(const int* __restrict__ dst, int* __restrict__ cnt,
                        int* __restrict__ rank, int E) {
  int e = blockIdx.x * 256 + threadIdx.x;
  if (e < E) rank[e] = atomicAdd(&cnt[dst[e]], 1);
}

__global__ void k_dinv(const int* __restrict__ cnt, float* __restrict__ dinv, int n) {
  int i = blockIdx.x * 256 + threadIdx.x;
  if (i < n) dinv[i] = rsqrtf((float)cnt[i] + 1.0f);   // +1 = self loop
}

// hierarchical exclusive scan of cnt -> row_start (512 elems per block)
__global__ void k_bsum(const int* __restrict__ cnt, int* __restrict__ bsum, int n) {
  __shared__ int red[256];
  int b = blockIdx.x, t = threadIdx.x;
  int i = b * 512 + t * 2;
  int s = ((i < n) ? cnt[i] : 0) + ((i + 1 < n) ? cnt[i + 1] : 0);
  red[t] = s;
  __syncthreads();
  for (int off = 128; off > 0; off >>= 1) {
    if (t < off) red[t] += red[t + off];
    __syncthreads();
  }
  if (t == 0) bsum[b] = red[0];
}

__global__ void k_bscan(int* __restrict__ bsum, int nb) {
  __shared__ int buf[1024];
  int t = threadIdx.x;
  int v = (t < nb) ? bsum[t] : 0;
  buf[t] = v;
  __syncthreads();
  for (int off = 1; off < 1024; off <<= 1) {
    int u = (t >= off) ? buf[t - off] : 0;
    __syncthreads();
    buf[t] += u;
    __syncthreads();
  }
  if (t < nb) bsum[t] = buf[t] - v;   // exclusive
}

__global__ void k_rowstart(const int* __restrict__ cnt, const int* __restrict__ bsum,
                           int* __restrict__ row_start, int n) {
  __shared__ int buf[256];
  int b = blockIdx.x, t = threadIdx.x;
  int i = b * 512 + t * 2;
  int c0 = (i < n) ? cnt[i] : 0;
  int c1 = (i + 1 < n) ? cnt[i + 1] : 0;
  int s = c0 + c1;
  buf[t] = s;
  __syncthreads();
  int mine = s;
  for (int off = 1; off < 256; off <<= 1) {
    int u = (t >= off) ? buf[t - off] : 0;
    __syncthreads();
    buf[t] += u;
    __syncthreads();
  }
  int ex = buf[t] - mine + bsum[b];
  if (i < n) row_start[i] = ex;
  if (i + 1 < n) row_start[i + 1] = ex + c0;
}

// atomic-free scatter: one 8B record per edge at row_start[dst] + rank[e]
__global__ void k_scatter(const int* __restrict__ src, const int* __restrict__ dst,
                          const int* __restrict__ row_start, const int* __restrict__ rank,
                          const float* __restrict__ dinv,
                          uint2* __restrict__ rec, int E) {
  int e = blockIdx.x * 256 + threadIdx.x;
  if (e < E) {
    int d = dst[e], s = src[e];
    int pos = row_start[d] + rank[e];
    union { float f; uint u; } w; w.f = dinv[s] * dinv[d];
    rec[pos] = make_uint2((uint)s, w.u);
  }
}

// ---------------- weight prep: bf16, MFMA-fragment-ordered ----------------
// Fragment layout: frag[(n*KS + ks)*512 + lane*8 + j] = W^T-element for
//   k = ks*32 + (lane>>4)*8 + j,  col = n*16 + (lane&15)
__global__ void k_prep_w(const float* __restrict__ lin_in_w,
                         const float* __restrict__ conv_w, const float* __restrict__ lin_w,
                         const float* __restrict__ conv_b, const float* __restrict__ lin_b,
                         ushort* __restrict__ wt_in, ushort* __restrict__ wt_l,
                         float* __restrict__ bsum, int L) {
  int tid = blockIdx.x * 256 + threadIdx.x;
  int total = L * 128 * 256;
  if (tid < total) {
    int l = tid >> 15;              // /32768
    int idx = tid & 32767;
    int n = idx >> 12;              // 8 col-blocks
    int r = idx & 4095;
    int ks = r >> 9;                // 8 k-steps (K=256)
    int r2 = r & 511;
    int lane = r2 >> 3;
    int j = r2 & 7;
    int k2 = ks * 32 + (lane >> 4) * 8 + j;
    int c = n * 16 + (lane & 15);
    float v = (k2 < 128) ? conv_w[((size_t)l * 128 + k2) * 128 + c]
                         : lin_w[((size_t)l * 128 + (k2 - 128)) * 128 + c];
    wt_l[tid] = f2bf(v);
  }
  if (tid < 128 * 128) {
    int n = tid >> 11;              // 8 col-blocks
    int r = tid & 2047;
    int ks = r >> 9;                // 4 k-steps (K=128)
    int r2 = r & 511;
    int lane = r2 >> 3;
    int j = r2 & 7;
    int k = ks * 32 + (lane >> 4) * 8 + j;
    int c = n * 16 + (lane & 15);
    wt_in[tid] = f2bf(lin_in_w[k * 128 + c]);
  }
  if (tid < L * 128) bsum[tid] = conv_b[tid] + lin_b[tid];
}

// ---------------- aggregation: s = D^-1/2 (A+I) D^-1/2 x  (bf16 in/out) ----------------
// one wave per node; 8-deep unrolled gather loop, tail-free (clamped index, zeroed
// weight). All 8 rec loads issue first (independent), then 8 row gathers in flight.
__global__ void k_agg(const ushort* __restrict__ X, const int* __restrict__ row_start,
                      const int* __restrict__ cnt, const float* __restrict__ dinv,
                      const uint2* __restrict__ rec, ushort* __restrict__ Sout, int n) {
  int node = blockIdx.x * 4 + (threadIdx.x >> 6);
  if (node >= n) return;
  int lane = threadIdx.x & 63;
  float dv = dinv[node];
  uint v = *reinterpret_cast<const uint*>(X + (size_t)node * HID + lane * 2);
  float ax = dv * dv * bf2f((ushort)(v & 0xffff));
  float ay = dv * dv * bf2f((ushort)(v >> 16));
  int start = row_start[node];
  int m = cnt[node];
  int last = start + m - 1;
  const ulong* recq = reinterpret_cast<const ulong*>(rec);

  for (int e = 0; e < m; e += 8) {
    int i0 = start + e;
    ulong q[8];
#pragma unroll
    for (int j = 0; j < 8; j++) q[j] = recq[min(i0 + j, last)];
    uint u[8];
#pragma unroll
    for (int j = 0; j < 8; j++)
      u[j] = *reinterpret_cast<const uint*>(X + (size_t)(uint)q[j] * HID + lane * 2);
#pragma unroll
    for (int j = 0; j < 8; j++) {
      union { uint u; float f; } w;
      w.u = (e + j < m) ? (uint)(q[j] >> 32) : 0u;
      ax = fmaf(w.f, bf2f((ushort)(u[j] & 0xffff)), ax);
      ay = fmaf(w.f, bf2f((ushort)(u[j] >> 16)), ay);
    }
  }
  uint o = (uint)f2bf(ax) | ((uint)f2bf(ay) << 16);
  *reinterpret_cast<uint*>(Sout + (size_t)node * HID + lane * 2) = o;
}

// ---------------- MFMA GEMM kernels ----------------
// per block: 4 waves, 16 rows each; per wave: full 128 output cols.
// A-frag: lane holds A[r0 + (l&15)][ks*32 + (l>>4)*8 .. +7]
// B-frag: coalesced from fragment-ordered WtF
// C: row=(l>>4)*4+q, col=n*16+(l&15) -> LDS transpose for coalesced epilogue

__global__ void __launch_bounds__(256, 2)
k_gemm_in(const float* __restrict__ Xin, const ushort* __restrict__ WtF,
          const float* __restrict__ bias, ushort* __restrict__ Xout, int nrows) {
  __shared__ float lds[4 * 16 * 132];
  const int tid = threadIdx.x;
  const int wid = tid >> 6, lane = tid & 63;
  const int lr = lane & 15, lg = lane >> 4;
  const int r0 = blockIdx.x * 64 + wid * 16;
  const int arow = r0 + lr;
  const bool rowok = arow < nrows;

  bf16x8 a[4];
  {
    const float* xp = Xin + (size_t)arow * HID + lg * 8;
#pragma unroll
    for (int ks = 0; ks < 4; ks++) {
      bf16x8 t;
#pragma unroll
      for (int i = 0; i < 8; i++) t[i] = 0;
      if (rowok) {
        float4 u0 = *reinterpret_cast<const float4*>(xp + ks * 32);
        float4 u1 = *reinterpret_cast<const float4*>(xp + ks * 32 + 4);
        t[0] = (short)f2bf(u0.x); t[1] = (short)f2bf(u0.y);
        t[2] = (short)f2bf(u0.z); t[3] = (short)f2bf(u0.w);
        t[4] = (short)f2bf(u1.x); t[5] = (short)f2bf(u1.y);
        t[6] = (short)f2bf(u1.z); t[7] = (short)f2bf(u1.w);
      }
      a[ks] = t;
    }
  }

  f32x4 acc[8];
#pragma unroll
  for (int n = 0; n < 8; n++) acc[n] = f32x4{0.f, 0.f, 0.f, 0.f};

  const ushort* wb = WtF + lane * 8;
#pragma unroll
  for (int n = 0; n < 8; n++)
#pragma unroll
    for (int ks = 0; ks < 4; ks++) {
      bf16x8 b = *reinterpret_cast<const bf16x8*>(wb + (n * 4 + ks) * 512);
      acc[n] = __builtin_amdgcn_mfma_f32_16x16x32_bf16(a[ks], b, acc[n], 0, 0, 0);
    }

  float* T = lds + wid * (16 * 132);
#pragma unroll
  for (int n = 0; n < 8; n++)
#pragma unroll
    for (int q = 0; q < 4; q++)
      T[(lg * 4 + q) * 132 + n * 16 + lr] = acc[n][q];

  const int c0 = lg * 32;
  const float* Trow = T + lr * 132 + c0;
  const int orow = r0 + lr;
  if (orow < nrows) {
    ushort* xo = Xout + (size_t)orow * HID + c0;
    uint pk[16];
#pragma unroll
    for (int j = 0; j < 8; j++) {
      float4 t = *reinterpret_cast<const float4*>(Trow + j * 4);
      float4 b4 = *reinterpret_cast<const float4*>(bias + c0 + j * 4);
      float o0 = t.x + b4.x, o1 = t.y + b4.y, o2 = t.z + b4.z, o3 = t.w + b4.w;
      pk[j * 2 + 0] = (uint)f2bf(o0) | ((uint)f2bf(o1) << 16);
      pk[j * 2 + 1] = (uint)f2bf(o2) | ((uint)f2bf(o3) << 16);
    }
#pragma unroll
    for (int j = 0; j < 4; j++)
      *reinterpret_cast<uint4*>(xo + j * 8) =
          make_uint4(pk[j * 4 + 0], pk[j * 4 + 1], pk[j * 4 + 2], pk[j * 4 + 3]);
  }
}

__global__ void __launch_bounds__(256, 2)
k_layer(const ushort* __restrict__ S, const ushort* __restrict__ Xin,
        ushort* __restrict__ Xout,
        const ushort* __restrict__ WtF, const float* __restrict__ bsum,
        const float* __restrict__ gamma, const float* __restrict__ beta, int nrows) {
  __shared__ float lds[4 * 16 * 132];
  const int tid = threadIdx.x;
  const int wid = tid >> 6, lane = tid & 63;
  const int lr = lane & 15, lg = lane >> 4;
  const int r0 = blockIdx.x * 64 + wid * 16;
  const int arow = r0 + lr;
  const bool rowok = arow < nrows;

  bf16x8 a[8];
  {
    const ushort* sp = S + (size_t)arow * HID + lg * 8;
    const ushort* xp = Xin + (size_t)arow * HID + lg * 8;
    bf16x8 z;
#pragma unroll
    for (int i = 0; i < 8; i++) z[i] = 0;
#pragma unroll
    for (int ks = 0; ks < 4; ks++)
      a[ks] = rowok ? *reinterpret_cast<const bf16x8*>(sp + ks * 32) : z;
#pragma unroll
    for (int ks = 0; ks < 4; ks++)
      a[4 + ks] = rowok ? *reinterpret_cast<const bf16x8*>(xp + ks * 32) : z;
  }

  f32x4 acc[8];
#pragma unroll
  for (int n = 0; n < 8; n++) acc[n] = f32x4{0.f, 0.f, 0.f, 0.f};

  const ushort* wb = WtF + lane * 8;
#pragma unroll
  for (int n = 0; n < 8; n++)
#pragma unroll
    for (int ks = 0; ks < 8; ks++) {
      bf16x8 b = *reinterpret_cast<const bf16x8*>(wb + (n * 8 + ks) * 512);
      acc[n] = __builtin_amdgcn_mfma_f32_16x16x32_bf16(a[ks], b, acc[n], 0, 0, 0);
    }

  float* T = lds + wid * (16 * 132);
#pragma unroll
  for (int n = 0; n < 8; n++)
#pragma unroll
    for (int q = 0; q < 4; q++)
      T[(lg * 4 + q) * 132 + n * 16 + lr] = acc[n][q];

  // epilogue: lane handles row lr, cols [c0, c0+32)
  const int c0 = lg * 32;
  const float* Trow = T + lr * 132 + c0;
  float v[32];
  float sum = 0.f, sq = 0.f;
#pragma unroll
  for (int j = 0; j < 8; j++) {
    float4 t = *reinterpret_cast<const float4*>(Trow + j * 4);
    float4 b4 = *reinterpret_cast<const float4*>(bsum + c0 + j * 4);
    float x0 = t.x + b4.x, x1 = t.y + b4.y, x2 = t.z + b4.z, x3 = t.w + b4.w;
    v[j * 4 + 0] = x0; v[j * 4 + 1] = x1; v[j * 4 + 2] = x2; v[j * 4 + 3] = x3;
    sum += (x0 + x1) + (x2 + x3);
    sq = fmaf(x0, x0, sq); sq = fmaf(x1, x1, sq);
    sq = fmaf(x2, x2, sq); sq = fmaf(x3, x3, sq);
  }
  sum += __shfl_xor(sum, 16); sq += __shfl_xor(sq, 16);
  sum += __shfl_xor(sum, 32); sq += __shfl_xor(sq, 32);
  const float mean = sum * (1.f / 128.f);
  const float rstd = rsqrtf(sq * (1.f / 128.f) - mean * mean + LN_EPS);

  const int orow = r0 + lr;
  if (orow < nrows) {
    ushort* xo = Xout + (size_t)orow * HID + c0;
    uint pk[16];
#pragma unroll
    for (int j = 0; j < 8; j++) {
      float4 g4 = *reinterpret_cast<const float4*>(gamma + c0 + j * 4);
      float4 b4 = *reinterpret_cast<const float4*>(beta + c0 + j * 4);
      float o0 = fmaxf(fmaf((v[j * 4 + 0] - mean) * rstd, g4.x, b4.x), 0.f);
      float o1 = fmaxf(fmaf((v[j * 4 + 1] - mean) * rstd, g4.y, b4.y), 0.f);
      float o2 = fmaxf(fmaf((v[j * 4 + 2] - mean) * rstd, g4.z, b4.z), 0.f);
      float o3 = fmaxf(fmaf((v[j * 4 + 3] - mean) * rstd, g4.w, b4.w), 0.f);
      pk[j * 2 + 0] = (uint)f2bf(o0) | ((uint)f2bf(o1) << 16);
      pk[j * 2 + 1] = (uint)f2bf(o2) | ((uint)f2bf(o3) << 16);
    }
#pragma unroll
    for (int j = 0; j < 4; j++)
      *reinterpret_cast<uint4*>(xo + j * 8) =
          make_uint4(pk[j * 4 + 0], pk[j * 4 + 1], pk[j * 4 + 2], pk[j * 4 + 3]);
  }
}

// ---------------- JK sum: out = x1 + x2 + x3 (bf16 -> f32) ----------------
__global__ void k_jk(const ushort* __restrict__ a, const ushort* __restrict__ b,
                     const ushort* __restrict__ c, float* __restrict__ out, int total8) {
  int i = blockIdx.x * 256 + threadIdx.x;
  if (i >= total8) return;
  uint4 ua = *reinterpret_cast<const uint4*>(a + (size_t)i * 8);
  uint4 ub = *reinterpret_cast<const uint4*>(b + (size_t)i * 8);
  uint4 uc = *reinterpret_cast<const uint4*>(c + (size_t)i * 8);
  float o[8];
  const uint pa[4] = {ua.x, ua.y, ua.z, ua.w};
  const uint pb[4] = {ub.x, ub.y, ub.z, ub.w};
  const uint pc[4] = {uc.x, uc.y, uc.z, uc.w};
#pragma unroll
  for (int j = 0; j < 4; j++) {
    o[j * 2 + 0] = bf2f((ushort)(pa[j] & 0xffff)) + bf2f((ushort)(pb[j] & 0xffff)) +
                   bf2f((ushort)(pc[j] & 0xffff));
    o[j * 2 + 1] = bf2f((ushort)(pa[j] >> 16)) + bf2f((ushort)(pb[j] >> 16)) +
                   bf2f((ushort)(pc[j] >> 16));
  }
  float* op = out + (size_t)i * 8;
  *reinterpret_cast<float4*>(op) = make_float4(o[0], o[1], o[2], o[3]);
  *reinterpret_cast<float4*>(op + 4) = make_float4(o[4], o[5], o[6], o[7]);
}

// ---------------- launcher ----------------

extern "C" void kernel_launch(void* const* d_in, const int* in_sizes, int n_in,
                              void* d_out, int out_size, void* d_ws, size_t ws_size,
                              hipStream_t stream) {
  const float* x_in     = (const float*)d_in[0];
  const int*   edge     = (const int*)d_in[1];
  const float* lin_in_w = (const float*)d_in[2];
  const float* lin_in_b = (const float*)d_in[3];
  const float* conv_w   = (const float*)d_in[4];
  const float* conv_b   = (const float*)d_in[5];
  const float* lin_w    = (const float*)d_in[6];
  const float* lin_b    = (const float*)d_in[7];
  const float* ln_g     = (const float*)d_in[8];
  const float* ln_b     = (const float*)d_in[9];

  int N = in_sizes[0] / HID;
  int E = in_sizes[1] / 2;
  int L = in_sizes[4] / (HID * HID);

  const int* src = edge;
  const int* dst = edge + E;

  char* ws = (char*)d_ws;
  size_t off = 0;
  auto alloc = [&](size_t bytes) -> void* {
    void* p = (void*)(ws + off);
    off += (bytes + 255) & ~(size_t)255;
    return p;
  };
  int*    cnt       = (int*)alloc((size_t)N * 4);
  int*    rank      = (int*)alloc((size_t)E * 4);
  int*    row_start = (int*)alloc((size_t)N * 4);
  float*  dinv      = (float*)alloc((size_t)N * 4);
  int*    blocksum  = (int*)alloc(4096);
  uint2*  rec       = (uint2*)alloc((size_t)E * 8);
  ushort* xb0       = (ushort*)alloc((size_t)N * HID * 2);
  ushort* xb1       = (ushort*)alloc((size_t)N * HID * 2);
  ushort* xb2       = (ushort*)alloc((size_t)N * HID * 2);
  ushort* sbuf      = (ushort*)alloc((size_t)N * HID * 2);
  ushort* wt_in     = (ushort*)alloc((size_t)128 * 128 * 2);
  ushort* wt_l      = (ushort*)alloc((size_t)L * 128 * 256 * 2);
  float*  bsum      = (float*)alloc((size_t)L * 128 * 4);
  (void)ws_size; (void)n_in; (void)out_size;

  int nb_n = (N + 255) / 256;
  int nb_e = (E + 255) / 256;
  int nbs  = (N + 511) / 512;
  int nb_g = (N + 63) / 64;
  int nb_w = (L * 128 * 256 + 255) / 256;
  int total8 = N * HID / 8;
  int nb_j = (total8 + 255) / 256;

  k_init<<<nb_n, 256, 0, stream>>>(cnt, N);
  k_count<<<nb_e, 256, 0, stream>>>(dst, cnt, rank, E);
  k_dinv<<<nb_n, 256, 0, stream>>>(cnt, dinv, N);
  k_bsum<<<nbs, 256, 0, stream>>>(cnt, blocksum, N);
  k_bscan<<<1, 1024, 0, stream>>>(blocksum, nbs);
  k_rowstart<<<nbs, 256, 0, stream>>>(cnt, blocksum, row_start, N);
  k_scatter<<<nb_e, 256, 0, stream>>>(src, dst, row_start, rank, dinv, rec, E);
  k_prep_w<<<nb_w, 256, 0, stream>>>(lin_in_w, conv_w, lin_w, conv_b, lin_b,
                                     wt_in, wt_l, bsum, L);

  k_gemm_in<<<nb_g, 256, 0, stream>>>(x_in, wt_in, lin_in_b, xb0, N);

  // rotate: layer i reads xprev, writes xcur; JK needs the 3 layer outputs
  ushort* xin_b[3]  = {xb0, xb1, xb2};
  ushort* xout_b[3] = {xb1, xb2, xb0};
  for (int i = 0; i < L; i++) {
    k_agg<<<(N + 3) / 4, 256, 0, stream>>>(xin_b[i], row_start, cnt, dinv, rec, sbuf, N);
    k_layer<<<nb_g, 256, 0, stream>>>(sbuf, xin_b[i], xout_b[i],
        wt_l + (size_t)i * 128 * 256, bsum + (size_t)i * 128,
        ln_g + (size_t)i * HID, ln_b + (size_t)i * HID, N);
  }
  k_jk<<<nb_j, 256, 0, stream>>>(xb1, xb2, xb0, (float*)d_out, total8);
}